// Round 1
// baseline (481.456 us; speedup 1.0000x reference)
//
#include <hip/hip_runtime.h>

// Problem constants (fixed by reference: B=4,S=4096,IN=1024,OUT=4096,RANK=32)
#define B_DIM 4
#define S_DIM 4096
#define IN_DIM 1024
#define OUT_DIM 4096
#define RANK_DIM 32

#define M_DIM (B_DIM * S_DIM)   // 16384
#define N_DIM OUT_DIM           // 4096
#define K_DIM IN_DIM            // 1024

typedef _Float16 h4 __attribute__((ext_vector_type(4)));
typedef _Float16 h8 __attribute__((ext_vector_type(8)));
typedef float f32x4 __attribute__((ext_vector_type(4)));

// Async global->LDS, 16B per lane. LDS dest = wave-uniform base + lane*16.
__device__ __forceinline__ void async_load16(const void* g, void* l) {
  __builtin_amdgcn_global_load_lds((const __attribute__((address_space(1))) void*)g,
                                   (__attribute__((address_space(3))) void*)l,
                                   16, 0, 0);
}

// ---------------------------------------------------------------------------
// Kernel 1: cast x (fp32) -> f16. 16,777,216 elems, 4/thread.
// ---------------------------------------------------------------------------
__global__ __launch_bounds__(256) void cvt_x_kernel(const float4* __restrict__ x,
                                                    h4* __restrict__ xh) {
  const int i = blockIdx.x * 256 + threadIdx.x;
  const float4 v = x[i];
  h4 o;
  o[0] = (_Float16)v.x; o[1] = (_Float16)v.y;
  o[2] = (_Float16)v.z; o[3] = (_Float16)v.w;
  xh[i] = o;
}

// ---------------------------------------------------------------------------
// Kernel 2: w_eff[n][k] = weight[n][k] + sum_r w1[src][n][r] * w2[tgt][r][k],
// cast to f16. One block per output row n; each thread owns one float4 of k.
// ---------------------------------------------------------------------------
__global__ __launch_bounds__(256) void prep_weff_kernel(
    const float* __restrict__ weight, const float* __restrict__ w1,
    const float* __restrict__ w2, const int* __restrict__ src_id,
    const int* __restrict__ tgt_id, h4* __restrict__ weff) {
  const int n = blockIdx.x;                 // 0..4095
  const int src = src_id[0];
  const int tgt = tgt_id[0];
  __shared__ float w1r[RANK_DIM];
  if (threadIdx.x < RANK_DIM)
    w1r[threadIdx.x] = w1[((size_t)src * OUT_DIM + n) * RANK_DIM + threadIdx.x];
  __syncthreads();
  const int k4 = threadIdx.x;               // 0..255 (= IN/4)
  float4 acc = ((const float4*)(weight + (size_t)n * IN_DIM))[k4];
  const float* w2t = w2 + (size_t)tgt * RANK_DIM * IN_DIM;
#pragma unroll 8
  for (int r = 0; r < RANK_DIM; ++r) {
    const float4 wv = ((const float4*)(w2t + (size_t)r * IN_DIM))[k4];
    const float c = w1r[r];
    acc.x += c * wv.x; acc.y += c * wv.y; acc.z += c * wv.z; acc.w += c * wv.w;
  }
  h4 o;
  o[0] = (_Float16)acc.x; o[1] = (_Float16)acc.y;
  o[2] = (_Float16)acc.z; o[3] = (_Float16)acc.w;
  weff[(size_t)n * (IN_DIM / 4) + k4] = o;
}

// ---------------------------------------------------------------------------
// Kernel 3: C[m][n] = sum_k A[m][k]*Bt[n][k] + bias[n], fp32 out.
// 128x128 tile / block (256 thr = 4 waves, each 64x64). BK=64.
// global_load_lds 16B staging; XOR-swizzled LDS columns (16B blocks) to keep
// ds_read_b128 fragment reads conflict-free (swizzle applied on the GLOBAL
// source column, since LDS dest of global_load_lds is fixed base+lane*16).
// ---------------------------------------------------------------------------
__global__ __launch_bounds__(256) void lms_gemm_kernel(
    const _Float16* __restrict__ A,   // [M][K] f16
    const _Float16* __restrict__ Bt,  // [N][K] f16
    const float* __restrict__ bias,   // [N]
    float* __restrict__ C) {          // [M][N]
  __shared__ _Float16 sA[128 * 64];
  __shared__ _Float16 sB[128 * 64];
  const int tid = threadIdx.x;
  const int wave = tid >> 6;
  const int lane = tid & 63;
  const int bn = blockIdx.x;  // 0..31
  const int bm = blockIdx.y;  // 0..127
  const int wm = wave & 1;    // 2x2 wave grid over the 128x128 tile
  const int wn = wave >> 1;

  f32x4 acc[4][4] = {};

  // Staging: wave w loads tile rows [w*32, w*32+32), 8 rows per issue.
  // lane -> (row = lane/8, col16B = lane%8); source col16B swizzled by row&7.
  const int srow = lane >> 3;                      // 0..7
  const int scol = ((lane & 7) ^ srow) * 8;        // swizzled global col (halfs)
  const _Float16* gA = A + ((size_t)(bm * 128 + wave * 32 + srow)) * K_DIM + scol;
  const _Float16* gB = Bt + ((size_t)(bn * 128 + wave * 32 + srow)) * K_DIM + scol;
  _Float16* lA = &sA[(wave * 32) * 64];
  _Float16* lB = &sB[(wave * 32) * 64];

  for (int k0 = 0; k0 < K_DIM; k0 += 64) {
#pragma unroll
    for (int i = 0; i < 4; ++i) {
      async_load16(gA + (size_t)i * 8 * K_DIM + k0, lA + i * 8 * 64);
      async_load16(gB + (size_t)i * 8 * K_DIM + k0, lB + i * 8 * 64);
    }
    __syncthreads();  // compiler emits vmcnt(0) drain before s_barrier

#pragma unroll
    for (int kk = 0; kk < 64; kk += 32) {
      h8 af[4], bf[4];
      // A-frag: lane holds A[m = lane&15][k = (lane>>4)*8 + j]
      // LDS col block for global block g at row r is (g ^ (r&7)); r&7 == lane&7.
      const int kq = (kk >> 3) + (lane >> 4);         // global 16B-block in window
      const int cs = (kq ^ (lane & 7)) * 8;           // swizzled LDS col (halfs)
#pragma unroll
      for (int mi = 0; mi < 4; ++mi)
        af[mi] = *(const h8*)&sA[(wm * 64 + mi * 16 + (lane & 15)) * 64 + cs];
#pragma unroll
      for (int ni = 0; ni < 4; ++ni)
        bf[ni] = *(const h8*)&sB[(wn * 64 + ni * 16 + (lane & 15)) * 64 + cs];
#pragma unroll
      for (int mi = 0; mi < 4; ++mi)
#pragma unroll
        for (int ni = 0; ni < 4; ++ni)
          acc[mi][ni] = __builtin_amdgcn_mfma_f32_16x16x32_f16(af[mi], bf[ni],
                                                               acc[mi][ni], 0, 0, 0);
    }
    __syncthreads();
  }

  // Epilogue: C/D layout col = lane&15, row = (lane>>4)*4 + r  [m89/m91]
  const int col0 = bn * 128 + wn * 64 + (lane & 15);
  const int row0 = bm * 128 + wm * 64 + ((lane >> 4) << 2);
#pragma unroll
  for (int ni = 0; ni < 4; ++ni) {
    const float bv = bias[col0 + ni * 16];
#pragma unroll
    for (int mi = 0; mi < 4; ++mi) {
      float* cp = C + (size_t)(row0 + mi * 16) * N_DIM + col0 + ni * 16;
#pragma unroll
      for (int r = 0; r < 4; ++r)
        cp[(size_t)r * N_DIM] = acc[mi][ni][r] + bv;
    }
  }
}

extern "C" void kernel_launch(void* const* d_in, const int* in_sizes, int n_in,
                              void* d_out, int out_size, void* d_ws, size_t ws_size,
                              hipStream_t stream) {
  const float* x      = (const float*)d_in[0];  // [4,4096,1024]
  const float* weight = (const float*)d_in[1];  // [4096,1024]
  const float* bias   = (const float*)d_in[2];  // [4096]
  const float* w1     = (const float*)d_in[3];  // [9,4096,32]
  const float* w2     = (const float*)d_in[4];  // [9,32,1024]
  const int* src_id   = (const int*)d_in[5];    // scalar
  const int* tgt_id   = (const int*)d_in[6];    // scalar
  float* out          = (float*)d_out;          // [4,4096,4096]

  // Workspace layout: x_f16 (32 MiB) | w_eff_f16 (8 MiB). Rewritten fully
  // every call (harness re-poisons d_ws).
  _Float16* xh   = (_Float16*)d_ws;
  _Float16* weff = xh + (size_t)M_DIM * K_DIM;

  cvt_x_kernel<<<(M_DIM * K_DIM) / 1024, 256, 0, stream>>>((const float4*)x, (h4*)xh);
  prep_weff_kernel<<<N_DIM, 256, 0, stream>>>(weight, w1, w2, src_id, tgt_id, (h4*)weff);

  dim3 grid(N_DIM / 128, M_DIM / 128);  // (32, 128)
  lms_gemm_kernel<<<grid, 256, 0, stream>>>(xh, weff, bias, out);
}

// Round 2
// 473.068 us; speedup vs baseline: 1.0177x; 1.0177x over previous
//
#include <hip/hip_runtime.h>

// Problem constants (fixed by reference: B=4,S=4096,IN=1024,OUT=4096,RANK=32)
#define B_DIM 4
#define S_DIM 4096
#define IN_DIM 1024
#define OUT_DIM 4096
#define RANK_DIM 32

#define M_DIM (B_DIM * S_DIM)   // 16384
#define N_DIM OUT_DIM           // 4096
#define K_DIM IN_DIM            // 1024

#define CVT_BLOCKS ((M_DIM * K_DIM) / 1024)  // 16384 blocks for x-cast

typedef _Float16 h4 __attribute__((ext_vector_type(4)));
typedef _Float16 h8 __attribute__((ext_vector_type(8)));
typedef float f32x16 __attribute__((ext_vector_type(16)));

// Async global->LDS, 16B per lane. LDS dest = wave-uniform base + lane*16.
__device__ __forceinline__ void async_load16(const void* g, void* l) {
  __builtin_amdgcn_global_load_lds((const __attribute__((address_space(1))) void*)g,
                                   (__attribute__((address_space(3))) void*)l,
                                   16, 0, 0);
}

// ---------------------------------------------------------------------------
// Fused prep: blocks [0, CVT_BLOCKS) cast x fp32->f16 (4 elems/thread);
// blocks [CVT_BLOCKS, CVT_BLOCKS+OUT_DIM) build one row of
// w_eff = weight + w1[src] @ w2[tgt], cast to f16.
// Fusing makes the combined cost visible as ONE dispatch in rocprof (round-1
// diagnostic: total 481 us vs gemm 180 us — where is the rest?).
// ---------------------------------------------------------------------------
__global__ __launch_bounds__(256) void prep_fused_kernel(
    const float4* __restrict__ x, h4* __restrict__ xh,
    const float* __restrict__ weight, const float* __restrict__ w1,
    const float* __restrict__ w2, const int* __restrict__ src_id,
    const int* __restrict__ tgt_id, h4* __restrict__ weff) {
  if (blockIdx.x < CVT_BLOCKS) {
    const int i = blockIdx.x * 256 + threadIdx.x;
    const float4 v = x[i];
    h4 o;
    o[0] = (_Float16)v.x; o[1] = (_Float16)v.y;
    o[2] = (_Float16)v.z; o[3] = (_Float16)v.w;
    xh[i] = o;
  } else {
    const int n = blockIdx.x - CVT_BLOCKS;    // 0..4095
    const int src = src_id[0];
    const int tgt = tgt_id[0];
    __shared__ float w1r[RANK_DIM];
    if (threadIdx.x < RANK_DIM)
      w1r[threadIdx.x] = w1[((size_t)src * OUT_DIM + n) * RANK_DIM + threadIdx.x];
    __syncthreads();
    const int k4 = threadIdx.x;               // 0..255 (= IN/4)
    float4 acc = ((const float4*)(weight + (size_t)n * IN_DIM))[k4];
    const float* w2t = w2 + (size_t)tgt * RANK_DIM * IN_DIM;
#pragma unroll 8
    for (int r = 0; r < RANK_DIM; ++r) {
      const float4 wv = ((const float4*)(w2t + (size_t)r * IN_DIM))[k4];
      const float c = w1r[r];
      acc.x += c * wv.x; acc.y += c * wv.y; acc.z += c * wv.z; acc.w += c * wv.w;
    }
    h4 o;
    o[0] = (_Float16)acc.x; o[1] = (_Float16)acc.y;
    o[2] = (_Float16)acc.z; o[3] = (_Float16)acc.w;
    weff[(size_t)n * (IN_DIM / 4) + k4] = o;
  }
}

// ---------------------------------------------------------------------------
// GEMM: C[m][n] = sum_k A[m][k]*Bt[n][k] + bias[n], fp32 out.
// 128x128 tile / block (256 thr = 4 waves, each 64x64 as 2x2 of 32x32).
// v_mfma_f32_32x32x16_f16: 18% fewer matrix-pipe cycles than 16x16x32
// (m119: 2495 vs 2075 TF ubench). BK=64, global_load_lds 16B staging,
// XOR-swizzled LDS 16B-columns (swizzle applied on the GLOBAL source column
// since global_load_lds's LDS dest is fixed base+lane*16). Round-1 measured
// SQ_LDS_BANK_CONFLICT = 0 with this scheme.
// ---------------------------------------------------------------------------
__global__ __launch_bounds__(256) void lms_gemm_kernel(
    const _Float16* __restrict__ A,   // [M][K] f16
    const _Float16* __restrict__ Bt,  // [N][K] f16
    const float* __restrict__ bias,   // [N]
    float* __restrict__ C) {          // [M][N]
  __shared__ _Float16 sA[128 * 64];
  __shared__ _Float16 sB[128 * 64];
  const int tid = threadIdx.x;
  const int wave = tid >> 6;
  const int lane = tid & 63;
  const int bn = blockIdx.x;  // 0..31
  const int bm = blockIdx.y;  // 0..127
  const int wm = wave & 1;    // 2x2 wave grid over the 128x128 tile
  const int wn = wave >> 1;

  f32x16 acc[2][2] = {};

  // Staging: wave w loads tile rows [w*32, w*32+32), 8 rows per issue.
  // lane -> (row = lane/8, col16B = lane%8); source col16B swizzled by row&7,
  // so LDS 16B-block b at row r holds global block (b ^ (r&7)).
  const int srow = lane >> 3;                      // 0..7
  const int scol = ((lane & 7) ^ srow) * 8;        // swizzled global col (halfs)
  const _Float16* gA = A + ((size_t)(bm * 128 + wave * 32 + srow)) * K_DIM + scol;
  const _Float16* gB = Bt + ((size_t)(bn * 128 + wave * 32 + srow)) * K_DIM + scol;
  _Float16* lA = &sA[(wave * 32) * 64];
  _Float16* lB = &sB[(wave * 32) * 64];

  for (int k0 = 0; k0 < K_DIM; k0 += 64) {
#pragma unroll
    for (int i = 0; i < 4; ++i) {
      async_load16(gA + (size_t)i * 8 * K_DIM + k0, lA + i * 8 * 64);
      async_load16(gB + (size_t)i * 8 * K_DIM + k0, lB + i * 8 * 64);
    }
    __syncthreads();  // compiler emits vmcnt(0) drain before s_barrier

#pragma unroll
    for (int ks = 0; ks < 4; ++ks) {   // K window 64 = 4 steps of K=16
      // A-frag (32x32x16): lane holds A[m = lane&31][k = (lane>>5)*8 + j].
      const int kq = ks * 2 + (lane >> 5);        // global 16B-block in window
      const int cs = (kq ^ (lane & 7)) * 8;       // swizzled LDS col (halfs)
      h8 af[2], bf[2];
#pragma unroll
      for (int mi = 0; mi < 2; ++mi)
        af[mi] = *(const h8*)&sA[(wm * 64 + mi * 32 + (lane & 31)) * 64 + cs];
#pragma unroll
      for (int ni = 0; ni < 2; ++ni)
        bf[ni] = *(const h8*)&sB[(wn * 64 + ni * 32 + (lane & 31)) * 64 + cs];
#pragma unroll
      for (int mi = 0; mi < 2; ++mi)
#pragma unroll
        for (int ni = 0; ni < 2; ++ni)
          acc[mi][ni] = __builtin_amdgcn_mfma_f32_32x32x16_f16(af[mi], bf[ni],
                                                               acc[mi][ni], 0, 0, 0);
    }
    __syncthreads();
  }

  // Epilogue: 32x32 C/D layout col = lane&31,
  // row = (reg&3) + 8*(reg>>2) + 4*(lane>>5)   [m74/m101]
  const int cn = lane & 31;
  const int rq = (lane >> 5) * 4;
#pragma unroll
  for (int ni = 0; ni < 2; ++ni) {
    const int col = bn * 128 + wn * 64 + ni * 32 + cn;
    const float bv = bias[col];
#pragma unroll
    for (int mi = 0; mi < 2; ++mi) {
      const int rowb = bm * 128 + wm * 64 + mi * 32 + rq;
      float* cp = C + (size_t)rowb * N_DIM + col;
#pragma unroll
      for (int reg = 0; reg < 16; ++reg) {
        const int roff = (reg & 3) + 8 * (reg >> 2);
        cp[(size_t)roff * N_DIM] = acc[mi][ni][reg] + bv;
      }
    }
  }
}

extern "C" void kernel_launch(void* const* d_in, const int* in_sizes, int n_in,
                              void* d_out, int out_size, void* d_ws, size_t ws_size,
                              hipStream_t stream) {
  const float* x      = (const float*)d_in[0];  // [4,4096,1024]
  const float* weight = (const float*)d_in[1];  // [4096,1024]
  const float* bias   = (const float*)d_in[2];  // [4096]
  const float* w1     = (const float*)d_in[3];  // [9,4096,32]
  const float* w2     = (const float*)d_in[4];  // [9,32,1024]
  const int* src_id   = (const int*)d_in[5];    // scalar
  const int* tgt_id   = (const int*)d_in[6];    // scalar
  float* out          = (float*)d_out;          // [4,4096,4096]

  // Workspace layout: x_f16 (32 MiB) | w_eff_f16 (8 MiB). Rewritten fully
  // every call (harness re-poisons d_ws).
  _Float16* xh   = (_Float16*)d_ws;
  _Float16* weff = xh + (size_t)M_DIM * K_DIM;

  prep_fused_kernel<<<CVT_BLOCKS + N_DIM, 256, 0, stream>>>(
      (const float4*)x, (h4*)xh, weight, w1, w2, src_id, tgt_id, (h4*)weff);

  dim3 grid(N_DIM / 128, M_DIM / 128);  // (32, 128)
  lms_gemm_kernel<<<grid, 256, 0, stream>>>(xh, weff, bias, out);
}